// Round 2
// baseline (426.659 us; speedup 1.0000x reference)
//
#include <hip/hip_runtime.h>
#include <hip/hip_bf16.h>

typedef unsigned int u32;
typedef unsigned short u16;

#define DEVINL __device__ __forceinline__

constexpr int Nn  = 25000;
constexpr int Ee  = 100000;
constexpr int NCc = 8000;
constexpr int Aa  = 50000;
constexpr int ECc = 24000;
constexpr int TCOLS = 1088;     // 34 k-rows * 32 o-cols
constexpr int WPSZ  = TCOLS*32; // one packed weight set
constexpr int TT_ROW = 561;     // u32 per T row: 32 o * 17 h-pair slots + 16 b2-pairs + 1 pad (odd mod 32)
constexpr int NB_N = (Nn + 255)/256;   // 98
constexpr int NB_C = (NCc + 255)/256;  // 32
// k_place_pack block ranges
constexpr int PB_EN = (Ee + 255)/256;     // 391  node edges
constexpr int PB_EC = (ECc + 255)/256;    // 94   clique edges
constexpr int PB_AS = (2*Aa + 255)/256;   // 391  assignment CSRs
constexpr int PB_WP = (4*WPSZ + 255)/256; // 544  weight packing

typedef float f32x4 __attribute__((ext_vector_type(4)));
typedef _Float16 h16x2 __attribute__((ext_vector_type(2)));
typedef _Float16 h16x8 __attribute__((ext_vector_type(8)));

DEVINL float b2f(u16 u){ union{u32 i;float f;}v; v.i = ((u32)u)<<16; return v.f; }
DEVINL float bfl(u32 u){ union{u32 i;float f;}v; v.i = u<<16; return v.f; }
DEVINL float bfh(u32 u){ union{u32 i;float f;}v; v.i = u & 0xffff0000u; return v.f; }
DEVINL u16 f2b(float f){ union{float f;u32 i;}v; v.f=f; u32 i=v.i;
  return (u16)((i + 0x7fffu + ((i>>16)&1u)) >> 16); }
DEVINL u16 f2h(float x){ union{ _Float16 h; u16 u; } v; v.h = (_Float16)x; return v.u; }
DEVINL u32 pkh2(float a, float b){
  union{ _Float16 h[2]; u32 u; } v;
  v.h[0] = (_Float16)a; v.h[1] = (_Float16)b; return v.u;
}
DEVINL float ldw(const void* p, long i, int f){
  return f ? ((const float*)p)[i] : b2f(((const u16*)p)[i]);
}
DEVINL float dot2f(u32 a, u32 b, float c){
  union U{u32 u; h16x2 h;};
  U ua; ua.u = a; U ub; ub.u = b;
#if __has_builtin(__builtin_amdgcn_fdot2)
  return __builtin_amdgcn_fdot2(ua.h, ub.h, c, false);
#else
  return c + (float)ua.h[0]*(float)ub.h[0] + (float)ua.h[1]*(float)ub.h[1];
#endif
}

// ---------- fused: dtype detect + all degree/count histograms ----------
__global__ __launch_bounds__(256) void k_detect_count(const u16* __restrict__ p, int n,
                        u32* __restrict__ maxbits, int* __restrict__ zcnt,
                        int* __restrict__ done, int* __restrict__ flag,
                        const int* __restrict__ ei, const int* __restrict__ cei,
                        const int* __restrict__ n2c,
                        int* __restrict__ deg_nd, int* __restrict__ deg_ce,
                        int* __restrict__ deg_n2c, int* __restrict__ deg_c2n,
                        int* __restrict__ cnt_sn, int* __restrict__ cnt_sc){
  int i0 = blockIdx.x*256 + threadIdx.x;
  // histogram part (range split)
  { int t = i0;
    if (t < Ee)                             atomicAdd(&deg_nd[ei[Ee + t]], 1);
    else if ((t -= Ee) < ECc)               atomicAdd(&deg_ce[cei[ECc + t]], 1);
    else if ((t -= ECc) < Aa)               atomicAdd(&deg_n2c[n2c[Aa + t]], 1);
    else if ((t -= Aa) < Aa)                atomicAdd(&deg_c2n[n2c[t]], 1);
    else if ((t -= Aa) < Ee)                atomicAdd(&cnt_sn[ei[t]], 1);
    else if ((t -= Ee) < ECc)               atomicAdd(&cnt_sc[cei[t]], 1);
  }
  // dtype detect part (grid-stride)
  float lm = 0.f; int lz = 0;
  for (int i = i0; i < n; i += gridDim.x*256){
    u16 v = p[i];
    if (v == 0) lz++;
    lm = fmaxf(lm, fabsf(b2f(v)));
  }
  #pragma unroll
  for (int off = 32; off; off >>= 1){
    lm = fmaxf(lm, __shfl_down(lm, off));
    lz += __shfl_down(lz, off);
  }
  if ((threadIdx.x & 63) == 0){
    atomicMax(maxbits, __float_as_uint(lm));
    atomicAdd(zcnt, lz);
  }
  __syncthreads();
  if (threadIdx.x == 0){
    __threadfence();
    if (atomicAdd(done, 1) == gridDim.x - 1){
      float m = __uint_as_float(*maxbits);
      *flag = (m > 1e6f || *zcnt > n/4) ? 1 : 0;   // 1 => f32 inputs
    }
  }
}

// ---------- hierarchical scan over 4 arrays: local pass ----------
__global__ __launch_bounds__(256) void k_scan_block(
    const int* __restrict__ c0, const int* __restrict__ c1,
    const int* __restrict__ c2, const int* __restrict__ c3,
    int* __restrict__ o0, int* __restrict__ o1, int* __restrict__ o2, int* __restrict__ o3,
    int* __restrict__ b0, int* __restrict__ b1, int* __restrict__ b2, int* __restrict__ b3){
  __shared__ int s[256];
  int bid = blockIdx.x, seg, rb;
  if (bid < NB_N){ seg=0; rb=bid; }
  else if (bid < NB_N+NB_C){ seg=1; rb=bid-NB_N; }
  else if (bid < 2*NB_N+NB_C){ seg=2; rb=bid-NB_N-NB_C; }
  else { seg=3; rb=bid-2*NB_N-NB_C; }
  const int* cnt = seg==0?c0 : seg==1?c1 : seg==2?c2 : c3;
  int* offs = seg==0?o0 : seg==1?o1 : seg==2?o2 : o3;
  int* bs   = seg==0?b0 : seg==1?b1 : seg==2?b2 : b3;
  int M = (seg & 1) ? NCc : Nn;
  int tid = threadIdx.x;
  int i = rb*256 + tid;
  int v = (i < M) ? cnt[i] : 0;
  s[tid] = v; __syncthreads();
  for (int d = 1; d < 256; d <<= 1){
    int t = (tid >= d) ? s[tid-d] : 0;
    __syncthreads();
    s[tid] += t;
    __syncthreads();
  }
  if (i < M) offs[i] = s[tid] - v;
  if (tid == 255) bs[rb] = s[255];
}

// ---------- fix pass with fused spine: each block redundantly reduces its prefix ----------
__global__ __launch_bounds__(256) void k_scan_fix2(
    int* __restrict__ o0, int* __restrict__ o1, int* __restrict__ o2, int* __restrict__ o3,
    const int* __restrict__ b0, const int* __restrict__ b1,
    const int* __restrict__ b2, const int* __restrict__ b3){
  __shared__ int s[256];
  int bid = blockIdx.x, seg, rb;
  if (bid < NB_N){ seg=0; rb=bid; }
  else if (bid < NB_N+NB_C){ seg=1; rb=bid-NB_N; }
  else if (bid < 2*NB_N+NB_C){ seg=2; rb=bid-NB_N-NB_C; }
  else { seg=3; rb=bid-2*NB_N-NB_C; }
  int* offs = seg==0?o0 : seg==1?o1 : seg==2?o2 : o3;
  const int* bsp = seg==0?b0 : seg==1?b1 : seg==2?b2 : b3;
  int M = (seg & 1) ? NCc : Nn;
  int tid = threadIdx.x;
  // exclusive prefix: sum of block sums [0, rb)
  int v = (tid < rb) ? bsp[tid] : 0;
  s[tid] = v; __syncthreads();
  #pragma unroll
  for (int d = 128; d; d >>= 1){
    if (tid < d) s[tid] += s[tid + d];
    __syncthreads();
  }
  int prefix = s[0];
  int i = rb*256 + tid;
  if (i < M) offs[i] += prefix;
}

// ---------- fused: place + payload pack (sorted sdp + hp for both layers) + weight pack ----------
__global__ __launch_bounds__(256) void k_place_pack(
    const int* __restrict__ ei, const int* __restrict__ cei, const int* __restrict__ n2c,
    const void* __restrict__ ef, const void* __restrict__ cef,
    const void* __restrict__ nn1w, const void* __restrict__ nn1b,
    const void* __restrict__ cnn1w, const void* __restrict__ cnn1b,
    const void* __restrict__ nn2w, const void* __restrict__ nn2b, const void* __restrict__ rootw,
    const void* __restrict__ cnn2w, const void* __restrict__ cnn2b, const void* __restrict__ crootw,
    const int* __restrict__ offs_n, const int* __restrict__ offs_c,
    const int* __restrict__ offs_an, const int* __restrict__ offs_ac,
    int* __restrict__ cur_n, int* __restrict__ cur_c,
    int* __restrict__ cur_an, int* __restrict__ cur_ac,
    int2* __restrict__ sdp_n, int2* __restrict__ sdp_c,
    u32* __restrict__ hp_n, u32* __restrict__ hp_c,
    int* __restrict__ an2c, int* __restrict__ ac2n,
    const int* __restrict__ flag, u16* __restrict__ Wp4){
  int b = blockIdx.x, tid = threadIdx.x;
  int f = *flag;
  if (b < PB_EN + PB_EC){
    // edge blocks: place + edge-MLP h for both layers, written at sorted position
    __shared__ float w1s[2][256], b1s[2][32];
    int isC = (b >= PB_EN);
    int e = (isC ? b - PB_EN : b)*256 + tid;
    int E = isC ? ECc : Ee;
    const void* W1 = isC ? cnn1w : nn1w;
    const void* B1 = isC ? cnn1b : nn1b;
    w1s[0][tid] = ldw(W1, tid, f);
    w1s[1][tid] = ldw(W1, 256 + tid, f);
    if (tid < 32){ b1s[0][tid] = ldw(B1, tid, f); b1s[1][tid] = ldw(B1, 32 + tid, f); }
    __syncthreads();
    if (e < E){
      const int* EI = isC ? cei : ei;
      int s = EI[e], d = EI[E + e];
      int* cur = isC ? cur_c : cur_n;
      const int* offs = isC ? offs_c : offs_n;
      int p = offs[s] + atomicAdd(&cur[s], 1);
      (isC ? sdp_c : sdp_n)[p] = make_int2(s, d);
      const void* EF = isC ? cef : ef;
      float ev[8];
      #pragma unroll
      for (int j = 0; j < 8; j++) ev[j] = ldw(EF, (long)e*8 + j, f);
      u32* hp = isC ? hp_c : hp_n;
      #pragma unroll
      for (int l = 0; l < 2; l++){
        u32* hq = hp + (size_t)l*E*16 + (size_t)p*16;
        #pragma unroll
        for (int kk = 0; kk < 16; kk++){
          float a0 = b1s[l][2*kk], a1 = b1s[l][2*kk+1];
          #pragma unroll
          for (int j = 0; j < 8; j++){
            a0 += ev[j]*w1s[l][j*32 + 2*kk];
            a1 += ev[j]*w1s[l][j*32 + 2*kk + 1];
          }
          hq[kk] = pkh2(fmaxf(a0, 0.f), fmaxf(a1, 0.f));
        }
      }
    }
  } else if (b < PB_EN + PB_EC + PB_AS){
    // assignment CSR placement
    int i = (b - PB_EN - PB_EC)*256 + tid;
    if (i < Aa){
      int c = n2c[Aa + i];
      an2c[offs_ac[c] + atomicAdd(&cur_ac[c], 1)] = n2c[i];
    } else if ((i -= Aa) < Aa){
      int nd = n2c[i];
      ac2n[offs_an[nd] + atomicAdd(&cur_an[nd], 1)] = n2c[Aa + i];
    }
  } else {
    // weight packing (f16)
    int i = (b - PB_EN - PB_EC - PB_AS)*256 + tid;
    if (i >= 4*WPSZ) return;
    int set = i / WPSZ, j = i - set*WPSZ;
    int l = set >> 1, isC = set & 1;
    const void* W2 = isC ? cnn2w : nn2w;
    const void* B2 = isC ? cnn2b : nn2b;
    const void* RW = isC ? crootw : rootw;
    int col = j >> 5, ii = j & 31;
    float v;
    if (col < 1024)      v = ldw(W2, (long)l*32768 + ((col>>5)<<10) + (ii<<5) + (col&31), f);
    else if (col < 1056) v = ldw(B2, (long)l*1024 + (ii<<5) + (col-1024), f);
    else                 v = ldw(RW, (long)l*1024 + (ii<<5) + (col-1056), f);
    Wp4[i] = f2h(v);
  }
}

// ---------- fused conv: f16 MFMA T (transposed h-pair layout) + dot2 streaming edges ----------
__global__ __launch_bounds__(512) void k_conv_fused(const void* __restrict__ base, int braw,
                           const float* __restrict__ addagg, const int* __restrict__ adddeg, int M,
                           const int2* __restrict__ sdp, const u32* __restrict__ hp,
                           const int* __restrict__ offs, int E_,
                           const u16* __restrict__ Wp,
                           const void* __restrict__ rb, long rboff,
                           const int* __restrict__ flag,
                           float* __restrict__ feat_root, float* __restrict__ agg){
  __shared__ __align__(16) u32 Tt[16*TT_ROW];
  __shared__ u32 hws[8][64];
  int tid = threadIdx.x;
  int w = tid >> 6, lane = tid & 63;
  int quad = lane >> 4, lm = lane & 15;
  int n0 = blockIdx.x * 16;
  int f = *flag;
  // x fragment: vectorized loads on both dtype paths
  int n = n0 + lm;
  int nc = n < M ? n : M-1;
  long bidx = (long)nc*32 + quad*8;
  float fv[8];
  if (braw && f == 0){
    uint4 q = *(const uint4*)((const u16*)base + bidx);
    fv[0]=bfl(q.x); fv[1]=bfh(q.x); fv[2]=bfl(q.y); fv[3]=bfh(q.y);
    fv[4]=bfl(q.z); fv[5]=bfh(q.z); fv[6]=bfl(q.w); fv[7]=bfh(q.w);
  } else {
    const float4* bp = (const float4*)((const float*)base + bidx);
    float4 q0 = bp[0], q1 = bp[1];
    fv[0]=q0.x; fv[1]=q0.y; fv[2]=q0.z; fv[3]=q0.w;
    fv[4]=q1.x; fv[5]=q1.y; fv[6]=q1.z; fv[7]=q1.w;
  }
  if (addagg){
    int dg = adddeg[nc];
    float d = (float)(dg > 1 ? dg : 1);
    const float4* ap = (const float4*)(addagg + (size_t)nc*32 + quad*8);
    float4 a0 = ap[0], a1 = ap[1];
    float inv = 1.f/d;
    fv[0]+=a0.x*inv; fv[1]+=a0.y*inv; fv[2]+=a0.z*inv; fv[3]+=a0.w*inv;
    fv[4]+=a1.x*inv; fv[5]+=a1.y*inv; fv[6]+=a1.z*inv; fv[7]+=a1.w*inv;
  }
  union { h16x8 v; u32 u[4]; } bf;
  #pragma unroll
  for (int j = 0; j < 4; j++) bf.u[j] = pkh2(fv[2*j], fv[2*j+1]);

  // phase 1: T tiles via f16 MFMA, stored transposed as (o-major, h-pair packed)
  #define AFR(ct) (*(const h16x8*)(Wp + (size_t)((ct)*16 + lm)*32 + quad*8))
  f32x4 z4 = {0.f, 0.f, 0.f, 0.f};
  #pragma unroll
  for (int g = 0; g < 2; g++){
    int q = w + 8*g;                  // q = h-pair index 0..15, covers ct 4q..4q+3
    f32x4 c0 = __builtin_amdgcn_mfma_f32_16x16x32_f16(AFR(4*q+0), bf.v, z4, 0, 0, 0);
    f32x4 c1 = __builtin_amdgcn_mfma_f32_16x16x32_f16(AFR(4*q+1), bf.v, z4, 0, 0, 0);
    f32x4 c2 = __builtin_amdgcn_mfma_f32_16x16x32_f16(AFR(4*q+2), bf.v, z4, 0, 0, 0);
    f32x4 c3 = __builtin_amdgcn_mfma_f32_16x16x32_f16(AFR(4*q+3), bf.v, z4, 0, 0, 0);
    int rbase = lm*TT_ROW;
    int ob = quad*4;
    #pragma unroll
    for (int i = 0; i < 4; i++){
      Tt[rbase + (ob+i)*17 + q]      = pkh2(c0[i], c2[i]);   // o = ob+i,   h = (2q, 2q+1)
      Tt[rbase + (16+ob+i)*17 + q]   = pkh2(c1[i], c3[i]);   // o = 16+ob+i
    }
  }
  if (w < 4){
    int ct = 64 + w;
    f32x4 c = __builtin_amdgcn_mfma_f32_16x16x32_f16(AFR(ct), bf.v, z4, 0, 0, 0);
    if (ct < 66){
      // b2 term: packed f16 pairs at row slots 544..559
      int p0 = (ct-64)*8 + quad*2;
      Tt[lm*TT_ROW + 544 + p0]     = pkh2(c[0], c[1]);
      Tt[lm*TT_ROW + 544 + p0 + 1] = pkh2(c[2], c[3]);
    } else if (n < M){
      int o = (ct-66)*16 + quad*4;
      float4 v = make_float4(c[0] + ldw(rb, rboff+o,   f),
                             c[1] + ldw(rb, rboff+o+1, f),
                             c[2] + ldw(rb, rboff+o+2, f),
                             c[3] + ldw(rb, rboff+o+3, f));
      *(float4*)&feat_root[(size_t)n*32 + o] = v;
    }
  }
  __syncthreads();

  // phase 2: streaming edges, 4/wave-iter, depth-2 prefetch, dot2 inner loop
  int lo = offs[n0];
  int hi = (n0 + 16 < M) ? offs[n0 + 16] : E_;
  int eg = quad, kk = lm;
  int pos = lo + w*4;
  u32 hp0 = 0, hp1 = 0; int sd0 = 0, sd1 = 0;
  { int idx = pos*16 + lane;      if (idx < hi*16) hp0 = hp[idx];
    idx = (pos+32)*16 + lane;     if (idx < hi*16) hp1 = hp[idx]; }
  if (lane < 8){
    int idx = pos*2 + lane;       if (idx < hi*2) sd0 = ((const int*)sdp)[idx];
    idx = (pos+32)*2 + lane;      if (idx < hi*2) sd1 = ((const int*)sdp)[idx];
  }
  for (; pos < hi; pos += 32){
    int np = pos + 64;
    u32 hp2 = 0; int sd2 = 0;
    { int idx = np*16 + lane; if (idx < hi*16) hp2 = hp[idx]; }
    if (lane < 8){ int idx = np*2 + lane; if (idx < hi*2) sd2 = ((const int*)sdp)[idx]; }
    hws[w][lane] = hp0;
    int sn = __shfl(sd0, 2*eg);
    int dn = __shfl(sd0, 2*eg + 1);
    bool valid = (pos + eg < hi);
    int sr = sn - n0; sr = sr < 0 ? 0 : (sr > 15 ? 15 : sr);
    const u32* Tr = Tt + sr*TT_ROW;
    const u32* T0 = Tr + 34*kk;            // o=2kk at +kq, o=2kk+1 at +17+kq
    const u32* Hp = &hws[w][eg*16];
    union{u32 u; h16x2 h;} b2u; b2u.u = Tr[544 + kk];
    float m0 = (float)b2u.h[0], m1 = (float)b2u.h[1];
    #pragma unroll
    for (int kq = 0; kq < 16; kq++){
      u32 hv = Hp[kq];
      u32 t0 = T0[kq];
      u32 t1 = T0[17 + kq];
      m0 = dot2f(hv, t0, m0);
      m1 = dot2f(hv, t1, m1);
    }
    if (valid){
      float* ap = agg + (size_t)dn*32 + 2*kk;
      atomicAdd(ap,   m0);
      atomicAdd(ap+1, m1);
    }
    hp0 = hp1; sd0 = sd1; hp1 = hp2; sd1 = sd2;
  }
  #undef AFR
}

// ---------- fused: feat = relu(agg/deg + froot); m = feat@w+b; scatter m into sagg ----------
__global__ __launch_bounds__(256) void k_update_lin(const float* __restrict__ agg, const int* __restrict__ deg,
                           const float* __restrict__ feat_root, int M,
                           const void* __restrict__ w, long woff,
                           const void* __restrict__ b, long boff,
                           const int* __restrict__ flag,
                           float* __restrict__ feat,
                           const int* __restrict__ sidx, const int* __restrict__ soffs,
                           const int* __restrict__ sdeg, float* __restrict__ sagg){
  __shared__ float wsm[1024], bs[32], rows[8][33];
  int tid = threadIdx.x;
  int f = *flag;
  for (int idx = tid; idx < 1024; idx += 256) wsm[idx] = ldw(w, woff + idx, f);
  if (tid < 32) bs[tid] = ldw(b, boff + tid, f);
  int nl = tid >> 5, o = tid & 31;
  int n = blockIdx.x*8 + nl;
  long i = (long)n*32 + o;
  if (n < M){
    int dg = deg[n];
    float d = (float)(dg > 1 ? dg : 1);
    float v = fmaxf(agg[i]/d + feat_root[i], 0.f);
    rows[nl][o] = v;
    feat[i] = v;
  }
  __syncthreads();
  if (n >= M) return;
  float acc = bs[o];
  #pragma unroll
  for (int j = 0; j < 32; j++) acc += rows[nl][j]*wsm[j*32+o];
  int slo = soffs[n], scnt = sdeg[n];
  for (int a = 0; a < scnt; a++)
    atomicAdd(&sagg[(size_t)sidx[slo + a]*32 + o], acc);
}

// ---------- final store ----------
__global__ __launch_bounds__(256) void k_store(const float* __restrict__ x, const float* __restrict__ xagg,
                      const int* __restrict__ xdeg, const float* __restrict__ c,
                      void* __restrict__ out, const int* __restrict__ flag){
  int i = blockIdx.x*256 + threadIdx.x;
  int tot = Nn*32 + NCc*32;
  if (i >= tot) return;
  float v;
  if (i < Nn*32){
    int n = i >> 5;
    int dg = xdeg[n];
    float d = (float)(dg > 1 ? dg : 1);
    v = x[i] + xagg[i]/d;
  } else v = c[i - Nn*32];
  if (*flag) ((float*)out)[i] = v;
  else       ((u16*)out)[i]   = f2b(v);
}

extern "C" void kernel_launch(void* const* d_in, const int* in_sizes, int n_in,
                              void* d_out, int out_size, void* d_ws, size_t ws_size,
                              hipStream_t stream){
  const int* ei  = (const int*)d_in[1];
  const int* n2c = (const int*)d_in[4];
  const int* cei = (const int*)d_in[5];
  const void *efr = d_in[2], *cefr = d_in[6];
  const void *nn1w = d_in[7], *nn1b = d_in[8], *nn2w = d_in[9], *nn2b = d_in[10],
             *rootw = d_in[11], *rootb = d_in[12], *n2cw = d_in[13], *n2cb = d_in[14],
             *cnn1w = d_in[15], *cnn1b = d_in[16], *cnn2w = d_in[17], *cnn2b = d_in[18],
             *crootw = d_in[19], *crootb = d_in[20], *c2nw = d_in[21], *c2nb = d_in[22];

  char* ws = (char*)d_ws;
  size_t off = 0;
  auto alloc = [&](size_t bytes){ void* p = ws + off; off += (bytes + 255) & ~(size_t)255; return p; };

  // ---- zeroed region (single memset) ----
  size_t zstart = off;
  float* aggE0  = (float*)alloc((size_t)Nn*32*4);
  float* aggE1  = (float*)alloc((size_t)Nn*32*4);
  float* caggE0 = (float*)alloc((size_t)NCc*32*4);
  float* caggE1 = (float*)alloc((size_t)NCc*32*4);
  float* caggS0 = (float*)alloc((size_t)NCc*32*4);
  float* caggS1 = (float*)alloc((size_t)NCc*32*4);
  float* aggS0  = (float*)alloc((size_t)Nn*32*4);
  float* aggS1  = (float*)alloc((size_t)Nn*32*4);
  int* deg_nd  = (int*)alloc((size_t)Nn*4);
  int* deg_ce  = (int*)alloc((size_t)NCc*4);
  int* deg_n2c = (int*)alloc((size_t)NCc*4);
  int* deg_c2n = (int*)alloc((size_t)Nn*4);
  int* cnt_sn  = (int*)alloc((size_t)Nn*4);
  int* cnt_sc  = (int*)alloc((size_t)NCc*4);
  int* cur_n   = (int*)alloc((size_t)Nn*4);
  int* cur_c   = (int*)alloc((size_t)NCc*4);
  int* cur_an  = (int*)alloc((size_t)Nn*4);
  int* cur_ac  = (int*)alloc((size_t)NCc*4);
  u32* maxbits = (u32*)alloc(256);
  int* zcnt = (int*)((char*)maxbits + 4);
  int* flag = (int*)((char*)maxbits + 8);
  int* done = (int*)((char*)maxbits + 12);
  size_t zbytes = off - zstart;

  // ---- non-zeroed ----
  float* xB  = (float*)alloc((size_t)Nn*32*4);
  float* xC  = (float*)alloc((size_t)Nn*32*4);
  float* cC0 = (float*)alloc((size_t)NCc*32*4);
  float* cC1 = (float*)alloc((size_t)NCc*32*4);
  float* frn = (float*)alloc((size_t)Nn*32*4);
  float* frc = (float*)alloc((size_t)NCc*32*4);
  int* offs_n  = (int*)alloc((size_t)Nn*4);
  int* offs_c  = (int*)alloc((size_t)NCc*4);
  int* offs_an = (int*)alloc((size_t)Nn*4);
  int* offs_ac = (int*)alloc((size_t)NCc*4);
  int* bs0 = (int*)alloc(512); int* bs1 = (int*)alloc(512);
  int* bs2 = (int*)alloc(512); int* bs3 = (int*)alloc(512);
  int* an2c = (int*)alloc((size_t)Aa*4);
  int* ac2n = (int*)alloc((size_t)Aa*4);
  int2* sdp_n = (int2*)alloc((size_t)Ee*8);
  int2* sdp_c = (int2*)alloc((size_t)ECc*8);
  u16* Wp4 = (u16*)alloc((size_t)4*WPSZ*2);
  u32* hp_n = (u32*)alloc((size_t)2*Ee*16*4);
  u32* hp_c = (u32*)alloc((size_t)2*ECc*16*4);

  auto nb = [](int n){ return (n + 255)/256; };

  // 1. memset accumulators/counters
  hipMemsetAsync(ws + zstart, 0, zbytes, stream);
  // 2. dtype detect + all histograms (fused)
  k_detect_count<<<nb(2*Ee + 2*ECc + 2*Aa),256,0,stream>>>((const u16*)d_in[0], Nn*32,
      maxbits, zcnt, done, flag, ei, cei, n2c,
      deg_nd, deg_ce, deg_n2c, deg_c2n, cnt_sn, cnt_sc);
  // 3. 4-way scan (2 dispatches: local + fused spine/fix)
  k_scan_block<<<2*(NB_N+NB_C),256,0,stream>>>(cnt_sn, cnt_sc, deg_c2n, deg_n2c,
      offs_n, offs_c, offs_an, offs_ac, bs0, bs1, bs2, bs3);
  k_scan_fix2<<<2*(NB_N+NB_C),256,0,stream>>>(offs_n, offs_c, offs_an, offs_ac,
      bs0, bs1, bs2, bs3);
  // 4. place + payload pack (sdp, hp both layers) + assignment CSRs + weight pack (fused)
  k_place_pack<<<PB_EN+PB_EC+PB_AS+PB_WP,256,0,stream>>>(ei, cei, n2c, efr, cefr,
      nn1w, nn1b, cnn1w, cnn1b, nn2w, nn2b, rootw, cnn2w, cnn2b, crootw,
      offs_n, offs_c, offs_an, offs_ac, cur_n, cur_c, cur_an, cur_ac,
      sdp_n, sdp_c, hp_n, hp_c, an2c, ac2n, flag, Wp4);

  int Gn = (Nn + 15)/16, Gc = (NCc + 15)/16;

  // ---- layer 0 ----
  k_conv_fused<<<Gn,512,0,stream>>>(d_in[0], 1, nullptr, nullptr, Nn, sdp_n, hp_n, offs_n, Ee,
      Wp4 + 0*WPSZ, rootb, 0, flag, frn, aggE0);
  k_update_lin<<<(Nn+7)/8,256,0,stream>>>(aggE0, deg_nd, frn, Nn, n2cw, 0, n2cb, 0, flag,
      xB, ac2n, offs_an, deg_c2n, caggS0);
  k_conv_fused<<<Gc,512,0,stream>>>(d_in[3], 1, caggS0, deg_n2c, NCc, sdp_c, hp_c, offs_c, ECc,
      Wp4 + 1*WPSZ, crootb, 0, flag, frc, caggE0);
  k_update_lin<<<(NCc+7)/8,256,0,stream>>>(caggE0, deg_ce, frc, NCc, c2nw, 0, c2nb, 0, flag,
      cC0, an2c, offs_ac, deg_n2c, aggS0);
  // ---- layer 1 ----
  k_conv_fused<<<Gn,512,0,stream>>>(xB, 0, aggS0, deg_c2n, Nn, sdp_n, hp_n + (size_t)Ee*16, offs_n, Ee,
      Wp4 + 2*WPSZ, rootb, 32, flag, frn, aggE1);
  k_update_lin<<<(Nn+7)/8,256,0,stream>>>(aggE1, deg_nd, frn, Nn, n2cw, 1024, n2cb, 32, flag,
      xC, ac2n, offs_an, deg_c2n, caggS1);
  k_conv_fused<<<Gc,512,0,stream>>>(cC0, 0, caggS1, deg_n2c, NCc, sdp_c, hp_c + (size_t)ECc*16, offs_c, ECc,
      Wp4 + 3*WPSZ, crootb, 32, flag, frc, caggE1);
  k_update_lin<<<(NCc+7)/8,256,0,stream>>>(caggE1, deg_ce, frc, NCc, c2nw, 1024, c2nb, 32, flag,
      cC1, an2c, offs_ac, deg_n2c, aggS1);
  // ---- output ----
  k_store<<<nb(Nn*32 + NCc*32),256,0,stream>>>(xC, aggS1, deg_c2n, cC1, d_out, flag);
}

// Round 3
// 294.483 us; speedup vs baseline: 1.4488x; 1.4488x over previous
//
#include <hip/hip_runtime.h>
#include <hip/hip_bf16.h>

typedef unsigned int u32;
typedef unsigned short u16;

#define DEVINL __device__ __forceinline__

constexpr int Nn  = 25000;
constexpr int Ee  = 100000;
constexpr int NCc = 8000;
constexpr int Aa  = 50000;
constexpr int ECc = 24000;
constexpr int TCOLS = 1088;     // 34 k-rows * 32 o-cols
constexpr int WPSZ  = TCOLS*32; // one packed weight set
constexpr int TT_ROW = 561;     // u32 per T row: 32 o * 17 h-pair slots + 16 b2-pairs + 1 pad (odd mod 32)
constexpr int NB_N = (Nn + 255)/256;   // 98
constexpr int NB_C = (NCc + 255)/256;  // 32
// k_place_pack block ranges
constexpr int PB_EN = (Ee + 255)/256;     // 391  node edges
constexpr int PB_EC = (ECc + 255)/256;    // 94   clique edges
constexpr int PB_AS = (2*Aa + 255)/256;   // 391  assignment CSRs
constexpr int PB_WP = (4*WPSZ + 255)/256; // 544  weight packing

typedef float f32x4 __attribute__((ext_vector_type(4)));
typedef _Float16 h16x2 __attribute__((ext_vector_type(2)));
typedef _Float16 h16x8 __attribute__((ext_vector_type(8)));

DEVINL float b2f(u16 u){ union{u32 i;float f;}v; v.i = ((u32)u)<<16; return v.f; }
DEVINL float bfl(u32 u){ union{u32 i;float f;}v; v.i = u<<16; return v.f; }
DEVINL float bfh(u32 u){ union{u32 i;float f;}v; v.i = u & 0xffff0000u; return v.f; }
DEVINL u16 f2b(float f){ union{float f;u32 i;}v; v.f=f; u32 i=v.i;
  return (u16)((i + 0x7fffu + ((i>>16)&1u)) >> 16); }
DEVINL u16 f2h(float x){ union{ _Float16 h; u16 u; } v; v.h = (_Float16)x; return v.u; }
DEVINL u32 pkh2(float a, float b){
  union{ _Float16 h[2]; u32 u; } v;
  v.h[0] = (_Float16)a; v.h[1] = (_Float16)b; return v.u;
}
DEVINL float ldw(const void* p, long i, int f){
  return f ? ((const float*)p)[i] : b2f(((const u16*)p)[i]);
}
DEVINL float dot2f(u32 a, u32 b, float c){
  union U{u32 u; h16x2 h;};
  U ua; ua.u = a; U ub; ub.u = b;
#if __has_builtin(__builtin_amdgcn_fdot2)
  return __builtin_amdgcn_fdot2(ua.h, ub.h, c, false);
#else
  return c + (float)ua.h[0]*(float)ub.h[0] + (float)ua.h[1]*(float)ub.h[1];
#endif
}

// ---------- fused: all histograms (full grid) + dtype detect (first 256 blocks, 1 atomic pair/block) ----------
__global__ __launch_bounds__(256) void k_detect_count(const u16* __restrict__ p, int n,
                        u32* __restrict__ maxbits, int* __restrict__ zcnt,
                        int* __restrict__ done, int* __restrict__ flag,
                        const int* __restrict__ ei, const int* __restrict__ cei,
                        const int* __restrict__ n2c,
                        int* __restrict__ deg_nd, int* __restrict__ deg_ce,
                        int* __restrict__ deg_n2c, int* __restrict__ deg_c2n,
                        int* __restrict__ cnt_sn, int* __restrict__ cnt_sc){
  int i0 = blockIdx.x*256 + threadIdx.x;
  // histogram part (range split over full grid; scattered addresses -> cheap)
  { int t = i0;
    if (t < Ee)                             atomicAdd(&deg_nd[ei[Ee + t]], 1);
    else if ((t -= Ee) < ECc)               atomicAdd(&deg_ce[cei[ECc + t]], 1);
    else if ((t -= ECc) < Aa)               atomicAdd(&deg_n2c[n2c[Aa + t]], 1);
    else if ((t -= Aa) < Aa)                atomicAdd(&deg_c2n[n2c[t]], 1);
    else if ((t -= Aa) < Ee)                atomicAdd(&cnt_sn[ei[t]], 1);
    else if ((t -= Ee) < ECc)               atomicAdd(&cnt_sc[cei[t]], 1);
  }
  // dtype detect part: ONLY first 256 blocks (contended same-line atomics scale with block count)
  if (blockIdx.x >= 256) return;
  float lm = 0.f; int lz = 0;
  for (int i = i0; i < n; i += 256*256){
    u16 v = p[i];
    if (v == 0) lz++;
    lm = fmaxf(lm, fabsf(b2f(v)));
  }
  #pragma unroll
  for (int off = 32; off; off >>= 1){
    lm = fmaxf(lm, __shfl_down(lm, off));
    lz += __shfl_down(lz, off);
  }
  __shared__ float smax[4]; __shared__ int szc[4];
  if ((threadIdx.x & 63) == 0){
    smax[threadIdx.x >> 6] = lm;
    szc[threadIdx.x >> 6] = lz;
  }
  __syncthreads();
  if (threadIdx.x == 0){
    float m = fmaxf(fmaxf(smax[0], smax[1]), fmaxf(smax[2], smax[3]));
    int z = szc[0] + szc[1] + szc[2] + szc[3];
    atomicMax(maxbits, __float_as_uint(m));
    atomicAdd(zcnt, z);
    __threadfence();
    if (atomicAdd(done, 1) == 255){
      float mm = __uint_as_float(*maxbits);
      *flag = (mm > 1e6f || *zcnt > n/4) ? 1 : 0;   // 1 => f32 inputs
    }
  }
}

// ---------- hierarchical scan over 4 arrays: local pass ----------
__global__ __launch_bounds__(256) void k_scan_block(
    const int* __restrict__ c0, const int* __restrict__ c1,
    const int* __restrict__ c2, const int* __restrict__ c3,
    int* __restrict__ o0, int* __restrict__ o1, int* __restrict__ o2, int* __restrict__ o3,
    int* __restrict__ b0, int* __restrict__ b1, int* __restrict__ b2, int* __restrict__ b3){
  __shared__ int s[256];
  int bid = blockIdx.x, seg, rb;
  if (bid < NB_N){ seg=0; rb=bid; }
  else if (bid < NB_N+NB_C){ seg=1; rb=bid-NB_N; }
  else if (bid < 2*NB_N+NB_C){ seg=2; rb=bid-NB_N-NB_C; }
  else { seg=3; rb=bid-2*NB_N-NB_C; }
  const int* cnt = seg==0?c0 : seg==1?c1 : seg==2?c2 : c3;
  int* offs = seg==0?o0 : seg==1?o1 : seg==2?o2 : o3;
  int* bs   = seg==0?b0 : seg==1?b1 : seg==2?b2 : b3;
  int M = (seg & 1) ? NCc : Nn;
  int tid = threadIdx.x;
  int i = rb*256 + tid;
  int v = (i < M) ? cnt[i] : 0;
  s[tid] = v; __syncthreads();
  for (int d = 1; d < 256; d <<= 1){
    int t = (tid >= d) ? s[tid-d] : 0;
    __syncthreads();
    s[tid] += t;
    __syncthreads();
  }
  if (i < M) offs[i] = s[tid] - v;
  if (tid == 255) bs[rb] = s[255];
}

// ---------- fix pass with fused spine: each block redundantly reduces its prefix ----------
__global__ __launch_bounds__(256) void k_scan_fix2(
    int* __restrict__ o0, int* __restrict__ o1, int* __restrict__ o2, int* __restrict__ o3,
    const int* __restrict__ b0, const int* __restrict__ b1,
    const int* __restrict__ b2, const int* __restrict__ b3){
  __shared__ int s[256];
  int bid = blockIdx.x, seg, rb;
  if (bid < NB_N){ seg=0; rb=bid; }
  else if (bid < NB_N+NB_C){ seg=1; rb=bid-NB_N; }
  else if (bid < 2*NB_N+NB_C){ seg=2; rb=bid-NB_N-NB_C; }
  else { seg=3; rb=bid-2*NB_N-NB_C; }
  int* offs = seg==0?o0 : seg==1?o1 : seg==2?o2 : o3;
  const int* bsp = seg==0?b0 : seg==1?b1 : seg==2?b2 : b3;
  int M = (seg & 1) ? NCc : Nn;
  int tid = threadIdx.x;
  // exclusive prefix: sum of block sums [0, rb)
  int v = (tid < rb) ? bsp[tid] : 0;
  s[tid] = v; __syncthreads();
  #pragma unroll
  for (int d = 128; d; d >>= 1){
    if (tid < d) s[tid] += s[tid + d];
    __syncthreads();
  }
  int prefix = s[0];
  int i = rb*256 + tid;
  if (i < M) offs[i] += prefix;
}

// ---------- fused: place + payload pack (sorted sdp + hp for both layers) + weight pack ----------
__global__ __launch_bounds__(256) void k_place_pack(
    const int* __restrict__ ei, const int* __restrict__ cei, const int* __restrict__ n2c,
    const void* __restrict__ ef, const void* __restrict__ cef,
    const void* __restrict__ nn1w, const void* __restrict__ nn1b,
    const void* __restrict__ cnn1w, const void* __restrict__ cnn1b,
    const void* __restrict__ nn2w, const void* __restrict__ nn2b, const void* __restrict__ rootw,
    const void* __restrict__ cnn2w, const void* __restrict__ cnn2b, const void* __restrict__ crootw,
    const int* __restrict__ offs_n, const int* __restrict__ offs_c,
    const int* __restrict__ offs_an, const int* __restrict__ offs_ac,
    int* __restrict__ cur_n, int* __restrict__ cur_c,
    int* __restrict__ cur_an, int* __restrict__ cur_ac,
    int2* __restrict__ sdp_n, int2* __restrict__ sdp_c,
    u32* __restrict__ hp_n, u32* __restrict__ hp_c,
    int* __restrict__ an2c, int* __restrict__ ac2n,
    const int* __restrict__ flag, u16* __restrict__ Wp4){
  int b = blockIdx.x, tid = threadIdx.x;
  int f = *flag;
  if (b < PB_EN + PB_EC){
    // edge blocks: place + edge-MLP h for both layers, written at sorted position
    __shared__ float w1s[2][256], b1s[2][32];
    int isC = (b >= PB_EN);
    int e = (isC ? b - PB_EN : b)*256 + tid;
    int E = isC ? ECc : Ee;
    const void* W1 = isC ? cnn1w : nn1w;
    const void* B1 = isC ? cnn1b : nn1b;
    w1s[0][tid] = ldw(W1, tid, f);
    w1s[1][tid] = ldw(W1, 256 + tid, f);
    if (tid < 32){ b1s[0][tid] = ldw(B1, tid, f); b1s[1][tid] = ldw(B1, 32 + tid, f); }
    __syncthreads();
    if (e < E){
      const int* EI = isC ? cei : ei;
      int s = EI[e], d = EI[E + e];
      int* cur = isC ? cur_c : cur_n;
      const int* offs = isC ? offs_c : offs_n;
      int p = offs[s] + atomicAdd(&cur[s], 1);
      (isC ? sdp_c : sdp_n)[p] = make_int2(s, d);
      const void* EF = isC ? cef : ef;
      float ev[8];
      #pragma unroll
      for (int j = 0; j < 8; j++) ev[j] = ldw(EF, (long)e*8 + j, f);
      u32* hp = isC ? hp_c : hp_n;
      #pragma unroll
      for (int l = 0; l < 2; l++){
        u32* hq = hp + (size_t)l*E*16 + (size_t)p*16;
        #pragma unroll
        for (int kk = 0; kk < 16; kk++){
          float a0 = b1s[l][2*kk], a1 = b1s[l][2*kk+1];
          #pragma unroll
          for (int j = 0; j < 8; j++){
            a0 += ev[j]*w1s[l][j*32 + 2*kk];
            a1 += ev[j]*w1s[l][j*32 + 2*kk + 1];
          }
          hq[kk] = pkh2(fmaxf(a0, 0.f), fmaxf(a1, 0.f));
        }
      }
    }
  } else if (b < PB_EN + PB_EC + PB_AS){
    // assignment CSR placement
    int i = (b - PB_EN - PB_EC)*256 + tid;
    if (i < Aa){
      int c = n2c[Aa + i];
      an2c[offs_ac[c] + atomicAdd(&cur_ac[c], 1)] = n2c[i];
    } else if ((i -= Aa) < Aa){
      int nd = n2c[i];
      ac2n[offs_an[nd] + atomicAdd(&cur_an[nd], 1)] = n2c[Aa + i];
    }
  } else {
    // weight packing (f16)
    int i = (b - PB_EN - PB_EC - PB_AS)*256 + tid;
    if (i >= 4*WPSZ) return;
    int set = i / WPSZ, j = i - set*WPSZ;
    int l = set >> 1, isC = set & 1;
    const void* W2 = isC ? cnn2w : nn2w;
    const void* B2 = isC ? cnn2b : nn2b;
    const void* RW = isC ? crootw : rootw;
    int col = j >> 5, ii = j & 31;
    float v;
    if (col < 1024)      v = ldw(W2, (long)l*32768 + ((col>>5)<<10) + (ii<<5) + (col&31), f);
    else if (col < 1056) v = ldw(B2, (long)l*1024 + (ii<<5) + (col-1024), f);
    else                 v = ldw(RW, (long)l*1024 + (ii<<5) + (col-1056), f);
    Wp4[i] = f2h(v);
  }
}

// ---------- fused conv: f16 MFMA T (transposed h-pair layout) + dot2 streaming edges ----------
__global__ __launch_bounds__(512) void k_conv_fused(const void* __restrict__ base, int braw,
                           const float* __restrict__ addagg, const int* __restrict__ adddeg, int M,
                           const int2* __restrict__ sdp, const u32* __restrict__ hp,
                           const int* __restrict__ offs, int E_,
                           const u16* __restrict__ Wp,
                           const void* __restrict__ rb, long rboff,
                           const int* __restrict__ flag,
                           float* __restrict__ feat_root, float* __restrict__ agg){
  __shared__ __align__(16) u32 Tt[16*TT_ROW];
  __shared__ u32 hws[8][64];
  int tid = threadIdx.x;
  int w = tid >> 6, lane = tid & 63;
  int quad = lane >> 4, lm = lane & 15;
  int n0 = blockIdx.x * 16;
  int f = *flag;
  // x fragment: vectorized loads on both dtype paths
  int n = n0 + lm;
  int nc = n < M ? n : M-1;
  long bidx = (long)nc*32 + quad*8;
  float fv[8];
  if (braw && f == 0){
    uint4 q = *(const uint4*)((const u16*)base + bidx);
    fv[0]=bfl(q.x); fv[1]=bfh(q.x); fv[2]=bfl(q.y); fv[3]=bfh(q.y);
    fv[4]=bfl(q.z); fv[5]=bfh(q.z); fv[6]=bfl(q.w); fv[7]=bfh(q.w);
  } else {
    const float4* bp = (const float4*)((const float*)base + bidx);
    float4 q0 = bp[0], q1 = bp[1];
    fv[0]=q0.x; fv[1]=q0.y; fv[2]=q0.z; fv[3]=q0.w;
    fv[4]=q1.x; fv[5]=q1.y; fv[6]=q1.z; fv[7]=q1.w;
  }
  if (addagg){
    int dg = adddeg[nc];
    float d = (float)(dg > 1 ? dg : 1);
    const float4* ap = (const float4*)(addagg + (size_t)nc*32 + quad*8);
    float4 a0 = ap[0], a1 = ap[1];
    float inv = 1.f/d;
    fv[0]+=a0.x*inv; fv[1]+=a0.y*inv; fv[2]+=a0.z*inv; fv[3]+=a0.w*inv;
    fv[4]+=a1.x*inv; fv[5]+=a1.y*inv; fv[6]+=a1.z*inv; fv[7]+=a1.w*inv;
  }
  union { h16x8 v; u32 u[4]; } bf;
  #pragma unroll
  for (int j = 0; j < 4; j++) bf.u[j] = pkh2(fv[2*j], fv[2*j+1]);

  // phase 1: T tiles via f16 MFMA, stored transposed as (o-major, h-pair packed)
  #define AFR(ct) (*(const h16x8*)(Wp + (size_t)((ct)*16 + lm)*32 + quad*8))
  f32x4 z4 = {0.f, 0.f, 0.f, 0.f};
  #pragma unroll
  for (int g = 0; g < 2; g++){
    int q = w + 8*g;                  // q = h-pair index 0..15, covers ct 4q..4q+3
    f32x4 c0 = __builtin_amdgcn_mfma_f32_16x16x32_f16(AFR(4*q+0), bf.v, z4, 0, 0, 0);
    f32x4 c1 = __builtin_amdgcn_mfma_f32_16x16x32_f16(AFR(4*q+1), bf.v, z4, 0, 0, 0);
    f32x4 c2 = __builtin_amdgcn_mfma_f32_16x16x32_f16(AFR(4*q+2), bf.v, z4, 0, 0, 0);
    f32x4 c3 = __builtin_amdgcn_mfma_f32_16x16x32_f16(AFR(4*q+3), bf.v, z4, 0, 0, 0);
    int rbase = lm*TT_ROW;
    int ob = quad*4;
    #pragma unroll
    for (int i = 0; i < 4; i++){
      Tt[rbase + (ob+i)*17 + q]      = pkh2(c0[i], c2[i]);   // o = ob+i,   h = (2q, 2q+1)
      Tt[rbase + (16+ob+i)*17 + q]   = pkh2(c1[i], c3[i]);   // o = 16+ob+i
    }
  }
  if (w < 4){
    int ct = 64 + w;
    f32x4 c = __builtin_amdgcn_mfma_f32_16x16x32_f16(AFR(ct), bf.v, z4, 0, 0, 0);
    if (ct < 66){
      // b2 term: packed f16 pairs at row slots 544..559
      int p0 = (ct-64)*8 + quad*2;
      Tt[lm*TT_ROW + 544 + p0]     = pkh2(c[0], c[1]);
      Tt[lm*TT_ROW + 544 + p0 + 1] = pkh2(c[2], c[3]);
    } else if (n < M){
      int o = (ct-66)*16 + quad*4;
      float4 v = make_float4(c[0] + ldw(rb, rboff+o,   f),
                             c[1] + ldw(rb, rboff+o+1, f),
                             c[2] + ldw(rb, rboff+o+2, f),
                             c[3] + ldw(rb, rboff+o+3, f));
      *(float4*)&feat_root[(size_t)n*32 + o] = v;
    }
  }
  __syncthreads();

  // phase 2: streaming edges, 4/wave-iter, depth-2 prefetch, dot2 inner loop
  int lo = offs[n0];
  int hi = (n0 + 16 < M) ? offs[n0 + 16] : E_;
  int eg = quad, kk = lm;
  int pos = lo + w*4;
  u32 hp0 = 0, hp1 = 0; int sd0 = 0, sd1 = 0;
  { int idx = pos*16 + lane;      if (idx < hi*16) hp0 = hp[idx];
    idx = (pos+32)*16 + lane;     if (idx < hi*16) hp1 = hp[idx]; }
  if (lane < 8){
    int idx = pos*2 + lane;       if (idx < hi*2) sd0 = ((const int*)sdp)[idx];
    idx = (pos+32)*2 + lane;      if (idx < hi*2) sd1 = ((const int*)sdp)[idx];
  }
  for (; pos < hi; pos += 32){
    int np = pos + 64;
    u32 hp2 = 0; int sd2 = 0;
    { int idx = np*16 + lane; if (idx < hi*16) hp2 = hp[idx]; }
    if (lane < 8){ int idx = np*2 + lane; if (idx < hi*2) sd2 = ((const int*)sdp)[idx]; }
    hws[w][lane] = hp0;
    int sn = __shfl(sd0, 2*eg);
    int dn = __shfl(sd0, 2*eg + 1);
    bool valid = (pos + eg < hi);
    int sr = sn - n0; sr = sr < 0 ? 0 : (sr > 15 ? 15 : sr);
    const u32* Tr = Tt + sr*TT_ROW;
    const u32* T0 = Tr + 34*kk;            // o=2kk at +kq, o=2kk+1 at +17+kq
    const u32* Hp = &hws[w][eg*16];
    union{u32 u; h16x2 h;} b2u; b2u.u = Tr[544 + kk];
    float m0 = (float)b2u.h[0], m1 = (float)b2u.h[1];
    #pragma unroll
    for (int kq = 0; kq < 16; kq++){
      u32 hv = Hp[kq];
      u32 t0 = T0[kq];
      u32 t1 = T0[17 + kq];
      m0 = dot2f(hv, t0, m0);
      m1 = dot2f(hv, t1, m1);
    }
    if (valid){
      float* ap = agg + (size_t)dn*32 + 2*kk;
      atomicAdd(ap,   m0);
      atomicAdd(ap+1, m1);
    }
    hp0 = hp1; sd0 = sd1; hp1 = hp2; sd1 = sd2;
  }
  #undef AFR
}

// ---------- fused: feat = relu(agg/deg + froot); m = feat@w+b; scatter m into sagg ----------
__global__ __launch_bounds__(256) void k_update_lin(const float* __restrict__ agg, const int* __restrict__ deg,
                           const float* __restrict__ feat_root, int M,
                           const void* __restrict__ w, long woff,
                           const void* __restrict__ b, long boff,
                           const int* __restrict__ flag,
                           float* __restrict__ feat,
                           const int* __restrict__ sidx, const int* __restrict__ soffs,
                           const int* __restrict__ sdeg, float* __restrict__ sagg){
  __shared__ float wsm[1024], bs[32], rows[8][33];
  int tid = threadIdx.x;
  int f = *flag;
  for (int idx = tid; idx < 1024; idx += 256) wsm[idx] = ldw(w, woff + idx, f);
  if (tid < 32) bs[tid] = ldw(b, boff + tid, f);
  int nl = tid >> 5, o = tid & 31;
  int n = blockIdx.x*8 + nl;
  long i = (long)n*32 + o;
  if (n < M){
    int dg = deg[n];
    float d = (float)(dg > 1 ? dg : 1);
    float v = fmaxf(agg[i]/d + feat_root[i], 0.f);
    rows[nl][o] = v;
    feat[i] = v;
  }
  __syncthreads();
  if (n >= M) return;
  float acc = bs[o];
  #pragma unroll
  for (int j = 0; j < 32; j++) acc += rows[nl][j]*wsm[j*32+o];
  int slo = soffs[n], scnt = sdeg[n];
  for (int a = 0; a < scnt; a++)
    atomicAdd(&sagg[(size_t)sidx[slo + a]*32 + o], acc);
}

// ---------- final store ----------
__global__ __launch_bounds__(256) void k_store(const float* __restrict__ x, const float* __restrict__ xagg,
                      const int* __restrict__ xdeg, const float* __restrict__ c,
                      void* __restrict__ out, const int* __restrict__ flag){
  int i = blockIdx.x*256 + threadIdx.x;
  int tot = Nn*32 + NCc*32;
  if (i >= tot) return;
  float v;
  if (i < Nn*32){
    int n = i >> 5;
    int dg = xdeg[n];
    float d = (float)(dg > 1 ? dg : 1);
    v = x[i] + xagg[i]/d;
  } else v = c[i - Nn*32];
  if (*flag) ((float*)out)[i] = v;
  else       ((u16*)out)[i]   = f2b(v);
}

extern "C" void kernel_launch(void* const* d_in, const int* in_sizes, int n_in,
                              void* d_out, int out_size, void* d_ws, size_t ws_size,
                              hipStream_t stream){
  const int* ei  = (const int*)d_in[1];
  const int* n2c = (const int*)d_in[4];
  const int* cei = (const int*)d_in[5];
  const void *efr = d_in[2], *cefr = d_in[6];
  const void *nn1w = d_in[7], *nn1b = d_in[8], *nn2w = d_in[9], *nn2b = d_in[10],
             *rootw = d_in[11], *rootb = d_in[12], *n2cw = d_in[13], *n2cb = d_in[14],
             *cnn1w = d_in[15], *cnn1b = d_in[16], *cnn2w = d_in[17], *cnn2b = d_in[18],
             *crootw = d_in[19], *crootb = d_in[20], *c2nw = d_in[21], *c2nb = d_in[22];

  char* ws = (char*)d_ws;
  size_t off = 0;
  auto alloc = [&](size_t bytes){ void* p = ws + off; off += (bytes + 255) & ~(size_t)255; return p; };

  // ---- zeroed region (single memset) ----
  size_t zstart = off;
  float* aggE0  = (float*)alloc((size_t)Nn*32*4);
  float* aggE1  = (float*)alloc((size_t)Nn*32*4);
  float* caggE0 = (float*)alloc((size_t)NCc*32*4);
  float* caggE1 = (float*)alloc((size_t)NCc*32*4);
  float* caggS0 = (float*)alloc((size_t)NCc*32*4);
  float* caggS1 = (float*)alloc((size_t)NCc*32*4);
  float* aggS0  = (float*)alloc((size_t)Nn*32*4);
  float* aggS1  = (float*)alloc((size_t)Nn*32*4);
  int* deg_nd  = (int*)alloc((size_t)Nn*4);
  int* deg_ce  = (int*)alloc((size_t)NCc*4);
  int* deg_n2c = (int*)alloc((size_t)NCc*4);
  int* deg_c2n = (int*)alloc((size_t)Nn*4);
  int* cnt_sn  = (int*)alloc((size_t)Nn*4);
  int* cnt_sc  = (int*)alloc((size_t)NCc*4);
  int* cur_n   = (int*)alloc((size_t)Nn*4);
  int* cur_c   = (int*)alloc((size_t)NCc*4);
  int* cur_an  = (int*)alloc((size_t)Nn*4);
  int* cur_ac  = (int*)alloc((size_t)NCc*4);
  u32* maxbits = (u32*)alloc(256);
  int* zcnt = (int*)((char*)maxbits + 4);
  int* flag = (int*)((char*)maxbits + 8);
  int* done = (int*)((char*)maxbits + 12);
  size_t zbytes = off - zstart;

  // ---- non-zeroed ----
  float* xB  = (float*)alloc((size_t)Nn*32*4);
  float* xC  = (float*)alloc((size_t)Nn*32*4);
  float* cC0 = (float*)alloc((size_t)NCc*32*4);
  float* cC1 = (float*)alloc((size_t)NCc*32*4);
  float* frn = (float*)alloc((size_t)Nn*32*4);
  float* frc = (float*)alloc((size_t)NCc*32*4);
  int* offs_n  = (int*)alloc((size_t)Nn*4);
  int* offs_c  = (int*)alloc((size_t)NCc*4);
  int* offs_an = (int*)alloc((size_t)Nn*4);
  int* offs_ac = (int*)alloc((size_t)NCc*4);
  int* bs0 = (int*)alloc(512); int* bs1 = (int*)alloc(512);
  int* bs2 = (int*)alloc(512); int* bs3 = (int*)alloc(512);
  int* an2c = (int*)alloc((size_t)Aa*4);
  int* ac2n = (int*)alloc((size_t)Aa*4);
  int2* sdp_n = (int2*)alloc((size_t)Ee*8);
  int2* sdp_c = (int2*)alloc((size_t)ECc*8);
  u16* Wp4 = (u16*)alloc((size_t)4*WPSZ*2);
  u32* hp_n = (u32*)alloc((size_t)2*Ee*16*4);
  u32* hp_c = (u32*)alloc((size_t)2*ECc*16*4);

  auto nb = [](int n){ return (n + 255)/256; };

  // 1. memset accumulators/counters
  hipMemsetAsync(ws + zstart, 0, zbytes, stream);
  // 2. dtype detect + all histograms (fused; detect gated to 256 blocks)
  k_detect_count<<<nb(2*Ee + 2*ECc + 2*Aa),256,0,stream>>>((const u16*)d_in[0], Nn*32,
      maxbits, zcnt, done, flag, ei, cei, n2c,
      deg_nd, deg_ce, deg_n2c, deg_c2n, cnt_sn, cnt_sc);
  // 3. 4-way scan (2 dispatches: local + fused spine/fix)
  k_scan_block<<<2*(NB_N+NB_C),256,0,stream>>>(cnt_sn, cnt_sc, deg_c2n, deg_n2c,
      offs_n, offs_c, offs_an, offs_ac, bs0, bs1, bs2, bs3);
  k_scan_fix2<<<2*(NB_N+NB_C),256,0,stream>>>(offs_n, offs_c, offs_an, offs_ac,
      bs0, bs1, bs2, bs3);
  // 4. place + payload pack (sdp, hp both layers) + assignment CSRs + weight pack (fused)
  k_place_pack<<<PB_EN+PB_EC+PB_AS+PB_WP,256,0,stream>>>(ei, cei, n2c, efr, cefr,
      nn1w, nn1b, cnn1w, cnn1b, nn2w, nn2b, rootw, cnn2w, cnn2b, crootw,
      offs_n, offs_c, offs_an, offs_ac, cur_n, cur_c, cur_an, cur_ac,
      sdp_n, sdp_c, hp_n, hp_c, an2c, ac2n, flag, Wp4);

  int Gn = (Nn + 15)/16, Gc = (NCc + 15)/16;

  // ---- layer 0 ----
  k_conv_fused<<<Gn,512,0,stream>>>(d_in[0], 1, nullptr, nullptr, Nn, sdp_n, hp_n, offs_n, Ee,
      Wp4 + 0*WPSZ, rootb, 0, flag, frn, aggE0);
  k_update_lin<<<(Nn+7)/8,256,0,stream>>>(aggE0, deg_nd, frn, Nn, n2cw, 0, n2cb, 0, flag,
      xB, ac2n, offs_an, deg_c2n, caggS0);
  k_conv_fused<<<Gc,512,0,stream>>>(d_in[3], 1, caggS0, deg_n2c, NCc, sdp_c, hp_c, offs_c, ECc,
      Wp4 + 1*WPSZ, crootb, 0, flag, frc, caggE0);
  k_update_lin<<<(NCc+7)/8,256,0,stream>>>(caggE0, deg_ce, frc, NCc, c2nw, 0, c2nb, 0, flag,
      cC0, an2c, offs_ac, deg_n2c, aggS0);
  // ---- layer 1 ----
  k_conv_fused<<<Gn,512,0,stream>>>(xB, 0, aggS0, deg_c2n, Nn, sdp_n, hp_n + (size_t)Ee*16, offs_n, Ee,
      Wp4 + 2*WPSZ, rootb, 32, flag, frn, aggE1);
  k_update_lin<<<(Nn+7)/8,256,0,stream>>>(aggE1, deg_nd, frn, Nn, n2cw, 1024, n2cb, 32, flag,
      xC, ac2n, offs_an, deg_c2n, caggS1);
  k_conv_fused<<<Gc,512,0,stream>>>(cC0, 0, caggS1, deg_n2c, NCc, sdp_c, hp_c + (size_t)ECc*16, offs_c, ECc,
      Wp4 + 3*WPSZ, crootb, 32, flag, frc, caggE1);
  k_update_lin<<<(NCc+7)/8,256,0,stream>>>(caggE1, deg_ce, frc, NCc, c2nw, 1024, c2nb, 32, flag,
      cC1, an2c, offs_ac, deg_n2c, aggS1);
  // ---- output ----
  k_store<<<nb(Nn*32 + NCc*32),256,0,stream>>>(xC, aggS1, deg_c2n, cC1, d_out, flag);
}

// Round 4
// 289.289 us; speedup vs baseline: 1.4749x; 1.0180x over previous
//
#include <hip/hip_runtime.h>
#include <hip/hip_bf16.h>

typedef unsigned int u32;
typedef unsigned short u16;

#define DEVINL __device__ __forceinline__

constexpr int Nn  = 25000;
constexpr int Ee  = 100000;
constexpr int NCc = 8000;
constexpr int Aa  = 50000;
constexpr int ECc = 24000;
constexpr int TCOLS = 1088;     // 34 k-rows * 32 o-cols
constexpr int WPSZ  = TCOLS*32; // one packed weight set
constexpr int TT_ROW = 561;     // u32 per T row: 32 o * 17 h-pair slots + 16 b2-pairs + 1 pad (odd mod 32)
constexpr int NB_N = (Nn + 255)/256;   // 98
constexpr int NB_C = (NCc + 255)/256;  // 32
// k_place_pack block ranges
constexpr int PB_EN = (Ee + 255)/256;     // 391  node edges
constexpr int PB_EC = (ECc + 255)/256;    // 94   clique edges
constexpr int PB_AS = (2*Aa + 255)/256;   // 391  assignment CSRs
constexpr int PB_WP = (4*WPSZ + 255)/256; // 544  weight packing

typedef float f32x4 __attribute__((ext_vector_type(4)));
typedef _Float16 h16x2 __attribute__((ext_vector_type(2)));
typedef _Float16 h16x8 __attribute__((ext_vector_type(8)));

DEVINL float b2f(u16 u){ union{u32 i;float f;}v; v.i = ((u32)u)<<16; return v.f; }
DEVINL float bfl(u32 u){ union{u32 i;float f;}v; v.i = u<<16; return v.f; }
DEVINL float bfh(u32 u){ union{u32 i;float f;}v; v.i = u & 0xffff0000u; return v.f; }
DEVINL u16 f2b(float f){ union{float f;u32 i;}v; v.f=f; u32 i=v.i;
  return (u16)((i + 0x7fffu + ((i>>16)&1u)) >> 16); }
DEVINL u16 f2h(float x){ union{ _Float16 h; u16 u; } v; v.h = (_Float16)x; return v.u; }
DEVINL u32 pkh2(float a, float b){
  union{ _Float16 h[2]; u32 u; } v;
  v.h[0] = (_Float16)a; v.h[1] = (_Float16)b; return v.u;
}
DEVINL float ldw(const void* p, long i, int f){
  return f ? ((const float*)p)[i] : b2f(((const u16*)p)[i]);
}
DEVINL float dot2f(u32 a, u32 b, float c){
  union U{u32 u; h16x2 h;};
  U ua; ua.u = a; U ub; ub.u = b;
#if __has_builtin(__builtin_amdgcn_fdot2)
  return __builtin_amdgcn_fdot2(ua.h, ub.h, c, false);
#else
  return c + (float)ua.h[0]*(float)ub.h[0] + (float)ua.h[1]*(float)ub.h[1];
#endif
}

// ---------- fused: all histograms (full grid) + dtype detect (first 256 blocks) ----------
__global__ __launch_bounds__(256) void k_detect_count(const u16* __restrict__ p, int n,
                        u32* __restrict__ maxbits, int* __restrict__ zcnt,
                        int* __restrict__ done, int* __restrict__ flag,
                        const int* __restrict__ ei, const int* __restrict__ cei,
                        const int* __restrict__ n2c,
                        int* __restrict__ deg_nd, int* __restrict__ deg_ce,
                        int* __restrict__ deg_n2c, int* __restrict__ deg_c2n,
                        int* __restrict__ cnt_sn, int* __restrict__ cnt_sc){
  int i0 = blockIdx.x*256 + threadIdx.x;
  { int t = i0;
    if (t < Ee)                             atomicAdd(&deg_nd[ei[Ee + t]], 1);
    else if ((t -= Ee) < ECc)               atomicAdd(&deg_ce[cei[ECc + t]], 1);
    else if ((t -= ECc) < Aa)               atomicAdd(&deg_n2c[n2c[Aa + t]], 1);
    else if ((t -= Aa) < Aa)                atomicAdd(&deg_c2n[n2c[t]], 1);
    else if ((t -= Aa) < Ee)                atomicAdd(&cnt_sn[ei[t]], 1);
    else if ((t -= Ee) < ECc)               atomicAdd(&cnt_sc[cei[t]], 1);
  }
  if (blockIdx.x >= 256) return;
  float lm = 0.f; int lz = 0;
  for (int i = i0; i < n; i += 256*256){
    u16 v = p[i];
    if (v == 0) lz++;
    lm = fmaxf(lm, fabsf(b2f(v)));
  }
  #pragma unroll
  for (int off = 32; off; off >>= 1){
    lm = fmaxf(lm, __shfl_down(lm, off));
    lz += __shfl_down(lz, off);
  }
  __shared__ float smax[4]; __shared__ int szc[4];
  if ((threadIdx.x & 63) == 0){
    smax[threadIdx.x >> 6] = lm;
    szc[threadIdx.x >> 6] = lz;
  }
  __syncthreads();
  if (threadIdx.x == 0){
    float m = fmaxf(fmaxf(smax[0], smax[1]), fmaxf(smax[2], smax[3]));
    int z = szc[0] + szc[1] + szc[2] + szc[3];
    atomicMax(maxbits, __float_as_uint(m));
    atomicAdd(zcnt, z);
    __threadfence();
    if (atomicAdd(done, 1) == 255){
      float mm = __uint_as_float(*maxbits);
      *flag = (mm > 1e6f || *zcnt > n/4) ? 1 : 0;   // 1 => f32 inputs
    }
  }
}

// ---------- 6-segment hierarchical scan: local pass ----------
DEVINL void segof(int bid, int& seg, int& rb){
  seg = 0; rb = bid;
  while (true){
    int nb = (seg & 1) ? NB_C : NB_N;
    if (rb < nb) break;
    rb -= nb; seg++;
  }
}

__global__ __launch_bounds__(256) void k_scan_block6(
    const int* __restrict__ c0, const int* __restrict__ c1,
    const int* __restrict__ c2, const int* __restrict__ c3,
    const int* __restrict__ c4, const int* __restrict__ c5,
    int* __restrict__ o0, int* __restrict__ o1, int* __restrict__ o2,
    int* __restrict__ o3, int* __restrict__ o4, int* __restrict__ o5,
    int* __restrict__ b0, int* __restrict__ b1, int* __restrict__ b2,
    int* __restrict__ b3, int* __restrict__ b4, int* __restrict__ b5){
  __shared__ int s[256];
  int seg, rb; segof(blockIdx.x, seg, rb);
  const int* cnt; int* offs; int* bs;
  switch (seg){
    case 0: cnt=c0; offs=o0; bs=b0; break;
    case 1: cnt=c1; offs=o1; bs=b1; break;
    case 2: cnt=c2; offs=o2; bs=b2; break;
    case 3: cnt=c3; offs=o3; bs=b3; break;
    case 4: cnt=c4; offs=o4; bs=b4; break;
    default: cnt=c5; offs=o5; bs=b5; break;
  }
  int M = (seg & 1) ? NCc : Nn;
  int tid = threadIdx.x;
  int i = rb*256 + tid;
  int v = (i < M) ? cnt[i] : 0;
  s[tid] = v; __syncthreads();
  for (int d = 1; d < 256; d <<= 1){
    int t = (tid >= d) ? s[tid-d] : 0;
    __syncthreads();
    s[tid] += t;
    __syncthreads();
  }
  if (i < M) offs[i] = s[tid] - v;
  if (tid == 255) bs[rb] = s[255];
}

// ---------- fix pass with fused spine ----------
__global__ __launch_bounds__(256) void k_scan_fix6(
    int* __restrict__ o0, int* __restrict__ o1, int* __restrict__ o2,
    int* __restrict__ o3, int* __restrict__ o4, int* __restrict__ o5,
    const int* __restrict__ b0, const int* __restrict__ b1, const int* __restrict__ b2,
    const int* __restrict__ b3, const int* __restrict__ b4, const int* __restrict__ b5){
  __shared__ int s[256];
  int seg, rb; segof(blockIdx.x, seg, rb);
  int* offs; const int* bsp;
  switch (seg){
    case 0: offs=o0; bsp=b0; break;
    case 1: offs=o1; bsp=b1; break;
    case 2: offs=o2; bsp=b2; break;
    case 3: offs=o3; bsp=b3; break;
    case 4: offs=o4; bsp=b4; break;
    default: offs=o5; bsp=b5; break;
  }
  int M = (seg & 1) ? NCc : Nn;
  int tid = threadIdx.x;
  int v = (tid < rb) ? bsp[tid] : 0;
  s[tid] = v; __syncthreads();
  #pragma unroll
  for (int d = 128; d; d >>= 1){
    if (tid < d) s[tid] += s[tid + d];
    __syncthreads();
  }
  int prefix = s[0];
  int i = rb*256 + tid;
  if (i < M) offs[i] += prefix;
}

// ---------- fused: place (src slot + dst slot) + payload pack + weight pack ----------
__global__ __launch_bounds__(256) void k_place_pack(
    const int* __restrict__ ei, const int* __restrict__ cei, const int* __restrict__ n2c,
    const void* __restrict__ ef, const void* __restrict__ cef,
    const void* __restrict__ nn1w, const void* __restrict__ nn1b,
    const void* __restrict__ cnn1w, const void* __restrict__ cnn1b,
    const void* __restrict__ nn2w, const void* __restrict__ nn2b, const void* __restrict__ rootw,
    const void* __restrict__ cnn2w, const void* __restrict__ cnn2b, const void* __restrict__ crootw,
    const int* __restrict__ offs_n, const int* __restrict__ offs_c,
    const int* __restrict__ offs_an, const int* __restrict__ offs_ac,
    const int* __restrict__ doffs_n, const int* __restrict__ doffs_c,
    int* __restrict__ cur_n, int* __restrict__ cur_c,
    int* __restrict__ cur_an, int* __restrict__ cur_ac,
    int* __restrict__ cur_dn, int* __restrict__ cur_dc,
    int2* __restrict__ sdp_n, int2* __restrict__ sdp_c,
    u32* __restrict__ hp_n, u32* __restrict__ hp_c,
    int* __restrict__ an2c, int* __restrict__ ac2n,
    const int* __restrict__ flag, u16* __restrict__ Wp4){
  int b = blockIdx.x, tid = threadIdx.x;
  int f = *flag;
  if (b < PB_EN + PB_EC){
    __shared__ float w1s[2][256], b1s[2][32];
    int isC = (b >= PB_EN);
    int e = (isC ? b - PB_EN : b)*256 + tid;
    int E = isC ? ECc : Ee;
    const void* W1 = isC ? cnn1w : nn1w;
    const void* B1 = isC ? cnn1b : nn1b;
    w1s[0][tid] = ldw(W1, tid, f);
    w1s[1][tid] = ldw(W1, 256 + tid, f);
    if (tid < 32){ b1s[0][tid] = ldw(B1, tid, f); b1s[1][tid] = ldw(B1, 32 + tid, f); }
    __syncthreads();
    if (e < E){
      const int* EI = isC ? cei : ei;
      int s = EI[e], d = EI[E + e];
      int* cur = isC ? cur_c : cur_n;
      const int* offs = isC ? offs_c : offs_n;
      int p = offs[s] + atomicAdd(&cur[s], 1);
      const int* dofs = isC ? doffs_c : doffs_n;
      int* curd = isC ? cur_dc : cur_dn;
      int dsl = dofs[d] + atomicAdd(&curd[d], 1);
      (isC ? sdp_c : sdp_n)[p] = make_int2(s, dsl);
      const void* EF = isC ? cef : ef;
      float ev[8];
      #pragma unroll
      for (int j = 0; j < 8; j++) ev[j] = ldw(EF, (long)e*8 + j, f);
      u32* hp = isC ? hp_c : hp_n;
      #pragma unroll
      for (int l = 0; l < 2; l++){
        u32* hq = hp + (size_t)l*E*16 + (size_t)p*16;
        #pragma unroll
        for (int kk = 0; kk < 16; kk++){
          float a0 = b1s[l][2*kk], a1 = b1s[l][2*kk+1];
          #pragma unroll
          for (int j = 0; j < 8; j++){
            a0 += ev[j]*w1s[l][j*32 + 2*kk];
            a1 += ev[j]*w1s[l][j*32 + 2*kk + 1];
          }
          hq[kk] = pkh2(fmaxf(a0, 0.f), fmaxf(a1, 0.f));
        }
      }
    }
  } else if (b < PB_EN + PB_EC + PB_AS){
    int i = (b - PB_EN - PB_EC)*256 + tid;
    if (i < Aa){
      int c = n2c[Aa + i];
      an2c[offs_ac[c] + atomicAdd(&cur_ac[c], 1)] = n2c[i];
    } else if ((i -= Aa) < Aa){
      int nd = n2c[i];
      ac2n[offs_an[nd] + atomicAdd(&cur_an[nd], 1)] = n2c[Aa + i];
    }
  } else {
    int i = (b - PB_EN - PB_EC - PB_AS)*256 + tid;
    if (i >= 4*WPSZ) return;
    int set = i / WPSZ, j = i - set*WPSZ;
    int l = set >> 1, isC = set & 1;
    const void* W2 = isC ? cnn2w : nn2w;
    const void* B2 = isC ? cnn2b : nn2b;
    const void* RW = isC ? crootw : rootw;
    int col = j >> 5, ii = j & 31;
    float v;
    if (col < 1024)      v = ldw(W2, (long)l*32768 + ((col>>5)<<10) + (ii<<5) + (col&31), f);
    else if (col < 1056) v = ldw(B2, (long)l*1024 + (ii<<5) + (col-1024), f);
    else                 v = ldw(RW, (long)l*1024 + (ii<<5) + (col-1056), f);
    Wp4[i] = f2h(v);
  }
}

// ---------- fused conv: f16 MFMA T + dot2 streaming edges; msg slot-store (no atomics) ----------
__global__ __launch_bounds__(512) void k_conv_fused(const void* __restrict__ base, int braw,
                           const float* __restrict__ adm, const int* __restrict__ sidx,
                           const int* __restrict__ soffs, const int* __restrict__ sdeg, int M,
                           const int2* __restrict__ sdp, const u32* __restrict__ hp,
                           const int* __restrict__ offs, int E_,
                           const u16* __restrict__ Wp,
                           const void* __restrict__ rb, long rboff,
                           const int* __restrict__ flag,
                           float* __restrict__ feat_root, float* __restrict__ msg){
  __shared__ __align__(16) u32 Tt[16*TT_ROW];
  __shared__ __align__(16) u32 hws[8][64];
  int tid = threadIdx.x;
  int w = tid >> 6, lane = tid & 63;
  int quad = lane >> 4, lm = lane & 15;
  int n0 = blockIdx.x * 16;
  int f = *flag;
  int n = n0 + lm;
  int nc = n < M ? n : M-1;
  long bidx = (long)nc*32 + quad*8;
  float fv[8];
  if (braw && f == 0){
    uint4 q = *(const uint4*)((const u16*)base + bidx);
    fv[0]=bfl(q.x); fv[1]=bfh(q.x); fv[2]=bfl(q.y); fv[3]=bfh(q.y);
    fv[4]=bfl(q.z); fv[5]=bfh(q.z); fv[6]=bfl(q.w); fv[7]=bfh(q.w);
  } else {
    const float4* bp = (const float4*)((const float*)base + bidx);
    float4 q0 = bp[0], q1 = bp[1];
    fv[0]=q0.x; fv[1]=q0.y; fv[2]=q0.z; fv[3]=q0.w;
    fv[4]=q1.x; fv[5]=q1.y; fv[6]=q1.z; fv[7]=q1.w;
  }
  if (adm){
    // gather-mean of dense m rows via CSR (replaces atomic-scattered S-buffer)
    int slo = soffs[nc], scnt = sdeg[nc];
    float ac[8] = {0,0,0,0,0,0,0,0};
    for (int k = 0; k < scnt; k++){
      const float4* mp = (const float4*)(adm + (size_t)sidx[slo + k]*32 + quad*8);
      float4 a0 = mp[0], a1 = mp[1];
      ac[0]+=a0.x; ac[1]+=a0.y; ac[2]+=a0.z; ac[3]+=a0.w;
      ac[4]+=a1.x; ac[5]+=a1.y; ac[6]+=a1.z; ac[7]+=a1.w;
    }
    float inv = 1.f/(float)(scnt > 1 ? scnt : 1);
    #pragma unroll
    for (int j = 0; j < 8; j++) fv[j] += ac[j]*inv;
  }
  union { h16x8 v; u32 u[4]; } bf;
  #pragma unroll
  for (int j = 0; j < 4; j++) bf.u[j] = pkh2(fv[2*j], fv[2*j+1]);

  // phase 1: T tiles via f16 MFMA, stored transposed as (o-major, h-pair packed)
  #define AFR(ct) (*(const h16x8*)(Wp + (size_t)((ct)*16 + lm)*32 + quad*8))
  f32x4 z4 = {0.f, 0.f, 0.f, 0.f};
  #pragma unroll
  for (int g = 0; g < 2; g++){
    int q = w + 8*g;
    f32x4 c0 = __builtin_amdgcn_mfma_f32_16x16x32_f16(AFR(4*q+0), bf.v, z4, 0, 0, 0);
    f32x4 c1 = __builtin_amdgcn_mfma_f32_16x16x32_f16(AFR(4*q+1), bf.v, z4, 0, 0, 0);
    f32x4 c2 = __builtin_amdgcn_mfma_f32_16x16x32_f16(AFR(4*q+2), bf.v, z4, 0, 0, 0);
    f32x4 c3 = __builtin_amdgcn_mfma_f32_16x16x32_f16(AFR(4*q+3), bf.v, z4, 0, 0, 0);
    int rbase = lm*TT_ROW;
    int ob = quad*4;
    #pragma unroll
    for (int i = 0; i < 4; i++){
      Tt[rbase + (ob+i)*17 + q]      = pkh2(c0[i], c2[i]);
      Tt[rbase + (16+ob+i)*17 + q]   = pkh2(c1[i], c3[i]);
    }
  }
  if (w < 4){
    int ct = 64 + w;
    f32x4 c = __builtin_amdgcn_mfma_f32_16x16x32_f16(AFR(ct), bf.v, z4, 0, 0, 0);
    if (ct < 66){
      int p0 = (ct-64)*8 + quad*2;
      Tt[lm*TT_ROW + 544 + p0]     = pkh2(c[0], c[1]);
      Tt[lm*TT_ROW + 544 + p0 + 1] = pkh2(c[2], c[3]);
    } else if (n < M){
      int o = (ct-66)*16 + quad*4;
      float4 v = make_float4(c[0] + ldw(rb, rboff+o,   f),
                             c[1] + ldw(rb, rboff+o+1, f),
                             c[2] + ldw(rb, rboff+o+2, f),
                             c[3] + ldw(rb, rboff+o+3, f));
      *(float4*)&feat_root[(size_t)n*32 + o] = v;
    }
  }
  __syncthreads();

  // phase 2: streaming edges, 4/wave-iter, depth-2 prefetch, dot2 inner loop
  int lo = offs[n0];
  int hi = (n0 + 16 < M) ? offs[n0 + 16] : E_;
  int eg = quad, kk = lm;
  int pos = lo + w*4;
  u32 hp0 = 0, hp1 = 0; int sd0 = 0, sd1 = 0;
  { int idx = pos*16 + lane;      if (idx < hi*16) hp0 = hp[idx];
    idx = (pos+32)*16 + lane;     if (idx < hi*16) hp1 = hp[idx]; }
  if (lane < 8){
    int idx = pos*2 + lane;       if (idx < hi*2) sd0 = ((const int*)sdp)[idx];
    idx = (pos+32)*2 + lane;      if (idx < hi*2) sd1 = ((const int*)sdp)[idx];
  }
  for (; pos < hi; pos += 32){
    int np = pos + 64;
    u32 hp2 = 0; int sd2 = 0;
    { int idx = np*16 + lane; if (idx < hi*16) hp2 = hp[idx]; }
    if (lane < 8){ int idx = np*2 + lane; if (idx < hi*2) sd2 = ((const int*)sdp)[idx]; }
    hws[w][lane] = hp0;
    int sn = __shfl(sd0, 2*eg);
    int ds = __shfl(sd0, 2*eg + 1);   // dst-CSR slot
    bool valid = (pos + eg < hi);
    int sr = sn - n0; sr = sr < 0 ? 0 : (sr > 15 ? 15 : sr);
    const u32* Tr = Tt + sr*TT_ROW;
    const u32* T0 = Tr + 34*kk;
    const uint4* Hp4 = (const uint4*)&hws[w][eg*16];
    union{u32 u; h16x2 h;} b2u; b2u.u = Tr[544 + kk];
    float m0 = (float)b2u.h[0], m1 = (float)b2u.h[1];
    #pragma unroll
    for (int g = 0; g < 4; g++){
      uint4 hv4 = Hp4[g];
      m0 = dot2f(hv4.x, T0[4*g+0], m0);  m1 = dot2f(hv4.x, T0[17+4*g+0], m1);
      m0 = dot2f(hv4.y, T0[4*g+1], m0);  m1 = dot2f(hv4.y, T0[17+4*g+1], m1);
      m0 = dot2f(hv4.z, T0[4*g+2], m0);  m1 = dot2f(hv4.z, T0[17+4*g+2], m1);
      m0 = dot2f(hv4.w, T0[4*g+3], m0);  m1 = dot2f(hv4.w, T0[17+4*g+3], m1);
    }
    if (valid){
      float* ap = msg + (size_t)ds*32 + 2*kk;   // plain coalesced 128B row store
      ap[0] = m0;
      ap[1] = m1;
    }
    hp0 = hp1; sd0 = sd1; hp1 = hp2; sd1 = sd2;
  }
  #undef AFR
}

// ---------- fused: agg = mean(msg rows); feat = relu(agg + froot); m = feat@w+b (dense store) ----------
__global__ __launch_bounds__(256) void k_update_lin(const float* __restrict__ msg,
                           const int* __restrict__ doffs, const int* __restrict__ deg,
                           const float* __restrict__ feat_root, int M,
                           const void* __restrict__ w, long woff,
                           const void* __restrict__ b, long boff,
                           const int* __restrict__ flag,
                           float* __restrict__ feat, float* __restrict__ mout){
  __shared__ float wsm[1024], bs[32], rows[8][33];
  int tid = threadIdx.x;
  int f = *flag;
  for (int idx = tid; idx < 1024; idx += 256) wsm[idx] = ldw(w, woff + idx, f);
  if (tid < 32) bs[tid] = ldw(b, boff + tid, f);
  int nl = tid >> 5, o = tid & 31;
  int n = blockIdx.x*8 + nl;
  long i = (long)n*32 + o;
  if (n < M){
    int lo = doffs[n], dg = deg[n];
    float a = 0.f;
    for (int k = 0; k < dg; k++) a += msg[(size_t)(lo + k)*32 + o];
    float d = (float)(dg > 1 ? dg : 1);
    float v = fmaxf(a/d + feat_root[i], 0.f);
    rows[nl][o] = v;
    feat[i] = v;
  }
  __syncthreads();
  if (n >= M) return;
  float acc = bs[o];
  #pragma unroll
  for (int j = 0; j < 32; j++) acc += rows[nl][j]*wsm[j*32+o];
  mout[i] = acc;
}

// ---------- final store: x + gather-mean(m_c) ----------
__global__ __launch_bounds__(256) void k_store(const float* __restrict__ x,
                      const float* __restrict__ mC, const int* __restrict__ sidx,
                      const int* __restrict__ soffs, const int* __restrict__ sdeg,
                      const float* __restrict__ c,
                      void* __restrict__ out, const int* __restrict__ flag){
  int i = blockIdx.x*256 + threadIdx.x;
  int tot = Nn*32 + NCc*32;
  if (i >= tot) return;
  float v;
  if (i < Nn*32){
    int n = i >> 5, o = i & 31;
    int lo = soffs[n], dg = sdeg[n];
    float a = 0.f;
    for (int k = 0; k < dg; k++) a += mC[(size_t)sidx[lo + k]*32 + o];
    v = x[i] + a/(float)(dg > 1 ? dg : 1);
  } else v = c[i - Nn*32];
  if (*flag) ((float*)out)[i] = v;
  else       ((u16*)out)[i]   = f2b(v);
}

extern "C" void kernel_launch(void* const* d_in, const int* in_sizes, int n_in,
                              void* d_out, int out_size, void* d_ws, size_t ws_size,
                              hipStream_t stream){
  const int* ei  = (const int*)d_in[1];
  const int* n2c = (const int*)d_in[4];
  const int* cei = (const int*)d_in[5];
  const void *efr = d_in[2], *cefr = d_in[6];
  const void *nn1w = d_in[7], *nn1b = d_in[8], *nn2w = d_in[9], *nn2b = d_in[10],
             *rootw = d_in[11], *rootb = d_in[12], *n2cw = d_in[13], *n2cb = d_in[14],
             *cnn1w = d_in[15], *cnn1b = d_in[16], *cnn2w = d_in[17], *cnn2b = d_in[18],
             *crootw = d_in[19], *crootb = d_in[20], *c2nw = d_in[21], *c2nb = d_in[22];

  char* ws = (char*)d_ws;
  size_t off = 0;
  auto alloc = [&](size_t bytes){ void* p = ws + off; off += (bytes + 255) & ~(size_t)255; return p; };

  // ---- zeroed region (counters only now; single small memset) ----
  size_t zstart = off;
  int* deg_nd  = (int*)alloc((size_t)Nn*4);
  int* deg_ce  = (int*)alloc((size_t)NCc*4);
  int* deg_n2c = (int*)alloc((size_t)NCc*4);
  int* deg_c2n = (int*)alloc((size_t)Nn*4);
  int* cnt_sn  = (int*)alloc((size_t)Nn*4);
  int* cnt_sc  = (int*)alloc((size_t)NCc*4);
  int* cur_n   = (int*)alloc((size_t)Nn*4);
  int* cur_c   = (int*)alloc((size_t)NCc*4);
  int* cur_an  = (int*)alloc((size_t)Nn*4);
  int* cur_ac  = (int*)alloc((size_t)NCc*4);
  int* cur_dn  = (int*)alloc((size_t)Nn*4);
  int* cur_dc  = (int*)alloc((size_t)NCc*4);
  u32* maxbits = (u32*)alloc(256);
  int* zcnt = (int*)((char*)maxbits + 4);
  int* flag = (int*)((char*)maxbits + 8);
  int* done = (int*)((char*)maxbits + 12);
  size_t zbytes = off - zstart;

  // ---- non-zeroed ----
  float* xB  = (float*)alloc((size_t)Nn*32*4);
  float* xC  = (float*)alloc((size_t)Nn*32*4);
  float* cC0 = (float*)alloc((size_t)NCc*32*4);
  float* cC1 = (float*)alloc((size_t)NCc*32*4);
  float* frn = (float*)alloc((size_t)Nn*32*4);
  float* frc = (float*)alloc((size_t)NCc*32*4);
  float* msgN = (float*)alloc((size_t)Ee*32*4);
  float* msgC = (float*)alloc((size_t)ECc*32*4);
  float* mN  = (float*)alloc((size_t)Nn*32*4);
  float* mC  = (float*)alloc((size_t)NCc*32*4);
  int* offs_n  = (int*)alloc((size_t)Nn*4);
  int* offs_c  = (int*)alloc((size_t)NCc*4);
  int* offs_an = (int*)alloc((size_t)Nn*4);
  int* offs_ac = (int*)alloc((size_t)NCc*4);
  int* doffs_n = (int*)alloc((size_t)Nn*4);
  int* doffs_c = (int*)alloc((size_t)NCc*4);
  int* bs0 = (int*)alloc(512); int* bs1 = (int*)alloc(512);
  int* bs2 = (int*)alloc(512); int* bs3 = (int*)alloc(512);
  int* bs4 = (int*)alloc(512); int* bs5 = (int*)alloc(512);
  int* an2c = (int*)alloc((size_t)Aa*4);
  int* ac2n = (int*)alloc((size_t)Aa*4);
  int2* sdp_n = (int2*)alloc((size_t)Ee*8);
  int2* sdp_c = (int2*)alloc((size_t)ECc*8);
  u16* Wp4 = (u16*)alloc((size_t)4*WPSZ*2);
  u32* hp_n = (u32*)alloc((size_t)2*Ee*16*4);
  u32* hp_c = (u32*)alloc((size_t)2*ECc*16*4);

  auto nb = [](int n){ return (n + 255)/256; };

  // 1. memset counters (~0.7 MB)
  hipMemsetAsync(ws + zstart, 0, zbytes, stream);
  // 2. dtype detect + all histograms
  k_detect_count<<<nb(2*Ee + 2*ECc + 2*Aa),256,0,stream>>>((const u16*)d_in[0], Nn*32,
      maxbits, zcnt, done, flag, ei, cei, n2c,
      deg_nd, deg_ce, deg_n2c, deg_c2n, cnt_sn, cnt_sc);
  // 3. 6-way scan (src CSRs, assignment CSRs, dst CSRs)
  k_scan_block6<<<3*(NB_N+NB_C),256,0,stream>>>(cnt_sn, cnt_sc, deg_c2n, deg_n2c, deg_nd, deg_ce,
      offs_n, offs_c, offs_an, offs_ac, doffs_n, doffs_c,
      bs0, bs1, bs2, bs3, bs4, bs5);
  k_scan_fix6<<<3*(NB_N+NB_C),256,0,stream>>>(offs_n, offs_c, offs_an, offs_ac, doffs_n, doffs_c,
      bs0, bs1, bs2, bs3, bs4, bs5);
  // 4. place (src+dst slots) + payload pack + assignment CSRs + weight pack
  k_place_pack<<<PB_EN+PB_EC+PB_AS+PB_WP,256,0,stream>>>(ei, cei, n2c, efr, cefr,
      nn1w, nn1b, cnn1w, cnn1b, nn2w, nn2b, rootw, cnn2w, cnn2b, crootw,
      offs_n, offs_c, offs_an, offs_ac, doffs_n, doffs_c,
      cur_n, cur_c, cur_an, cur_ac, cur_dn, cur_dc,
      sdp_n, sdp_c, hp_n, hp_c, an2c, ac2n, flag, Wp4);

  int Gn = (Nn + 15)/16, Gc = (NCc + 15)/16;

  // ---- layer 0 ----
  k_conv_fused<<<Gn,512,0,stream>>>(d_in[0], 1, nullptr, nullptr, nullptr, nullptr, Nn,
      sdp_n, hp_n, offs_n, Ee, Wp4 + 0*WPSZ, rootb, 0, flag, frn, msgN);
  k_update_lin<<<(Nn+7)/8,256,0,stream>>>(msgN, doffs_n, deg_nd, frn, Nn,
      n2cw, 0, n2cb, 0, flag, xB, mN);
  k_conv_fused<<<Gc,512,0,stream>>>(d_in[3], 1, mN, an2c, offs_ac, deg_n2c, NCc,
      sdp_c, hp_c, offs_c, ECc, Wp4 + 1*WPSZ, crootb, 0, flag, frc, msgC);
  k_update_lin<<<(NCc+7)/8,256,0,stream>>>(msgC, doffs_c, deg_ce, frc, NCc,
      c2nw, 0, c2nb, 0, flag, cC0, mC);
  // ---- layer 1 ----
  k_conv_fused<<<Gn,512,0,stream>>>(xB, 0, mC, ac2n, offs_an, deg_c2n, Nn,
      sdp_n, hp_n + (size_t)Ee*16, offs_n, Ee, Wp4 + 2*WPSZ, rootb, 32, flag, frn, msgN);
  k_update_lin<<<(Nn+7)/8,256,0,stream>>>(msgN, doffs_n, deg_nd, frn, Nn,
      n2cw, 1024, n2cb, 32, flag, xC, mN);
  k_conv_fused<<<Gc,512,0,stream>>>(cC0, 0, mN, an2c, offs_ac, deg_n2c, NCc,
      sdp_c, hp_c + (size_t)ECc*16, offs_c, ECc, Wp4 + 3*WPSZ, crootb, 32, flag, frc, msgC);
  k_update_lin<<<(NCc+7)/8,256,0,stream>>>(msgC, doffs_c, deg_ce, frc, NCc,
      c2nw, 1024, c2nb, 32, flag, cC1, mC);
  // ---- output ----
  k_store<<<nb(Nn*32 + NCc*32),256,0,stream>>>(xC, mC, ac2n, offs_an, deg_c2n, cC1, d_out, flag);
}